// Round 3
// baseline (1553.571 us; speedup 1.0000x reference)
//
#include <hip/hip_runtime.h>

// 2-layer LSTM encoder, B=128, T=1024, F=1, HID=128, EMB=64.
// R12 = wave specialization (R10) + L2 lag-2 register prefetch:
//   R10/R9 null-vs-each-other + R11 failure localize the bottleneck: step =
//   1086cy matrix-pipe + ~600cy lockstep tail (post-barrier ds_read latency +
//   ew+write tail). R12 attacks the tail:
//   - L2 (waves 0-3) consumes h1(s-2) from REGISTERS (RA/RB ping-pong),
//     prefetched during step s-1 -> at barrier release L2 issues 16 ih-MFMAs
//     with ZERO wait, feeding the matrix pipe while L1 waves wait ~130cy for
//     their a1 ds_read. hh-MFMAs (a2, lag-1 read at top) issue ~310cy in,
//     latency hidden under ih pipe time.
//   - L1 (waves 4-7) unchanged: 32 MFMAs depth-4, ew on 32 lanes.
//   - main loop unrolled x2: LDS slots and RA/RB roles are compile-time.
//   - L2 lags L1 by 2 steps -> 2 L2-only epilogue iters (h2(1022), h2(1023)).
// Schedule: iter s: L1 computes h1(s) [s in 1..1023]; L2 computes h2(s-2)
//   [s in 2..1025]. h1(m) -> H1[m&1]; h2(m) -> H2[m&1].
//   L2 at iter s: a2 = h2(s-3) read from H2[(s-1)&1] at top; a1p = h1(s-2)
//   in regs; prefetch h1(s-1) from H1[(s-1)&1] for next iter.
// Verified-passing gate/cell index maps from R10 are kept verbatim.

#define TB   1024
#define HID1 128
#define EMB2 64

typedef _Float16 f16x8 __attribute__((ext_vector_type(8)));
typedef float    f32x4 __attribute__((ext_vector_type(4)));

#define MFMA16(a,b,c) __builtin_amdgcn_mfma_f32_16x16x32_f16((a),(b),(c),0,0,0)

static __device__ __forceinline__ float fast_exp2(float x){
#if __has_builtin(__builtin_amdgcn_exp2f)
  return __builtin_amdgcn_exp2f(x);
#else
  return __exp2f(x);
#endif
}
static __device__ __forceinline__ float fast_rcp(float x){
#if __has_builtin(__builtin_amdgcn_rcpf)
  return __builtin_amdgcn_rcpf(x);
#else
  return 1.0f / x;
#endif
}
static __device__ __forceinline__ float sigmoid_f(float x){
  return fast_rcp(1.0f + fast_exp2(-1.44269504088896340736f * x));
}
static __device__ __forceinline__ float tanh_f(float x){
  return 1.0f - 2.0f * fast_rcp(1.0f + fast_exp2(2.88539008177792681472f * x));
}

static __device__ __forceinline__ f16x8 load_frag(const float* p){
  f16x8 r;
  #pragma unroll
  for (int j = 0; j < 8; ++j) r[j] = (_Float16)p[j];
  return r;
}

__launch_bounds__(512, 2)
__global__ void lstm2_kernel(const float* __restrict__ x,
                             const float* __restrict__ w_ih1,
                             const float* __restrict__ w_hh1,
                             const float* __restrict__ b_ih1,
                             const float* __restrict__ b_hh1,
                             const float* __restrict__ w_ih2,
                             const float* __restrict__ w_hh2,
                             const float* __restrict__ b_ih2,
                             const float* __restrict__ b_hh2,
                             float* __restrict__ out)
{
  __shared__ __align__(16) float    xs[TB];
  __shared__ __align__(16) _Float16 H1[2][HID1];  // h1 ping-pong
  __shared__ __align__(16) _Float16 H2[2][EMB2];  // h2 ping-pong

  const int t    = threadIdx.x;   // 0..511
  const int b    = blockIdx.x;    // 0..127
  const int l    = t & 63;        // lane
  const int w    = t >> 6;        // wave 0..7
  const int col  = l & 15;
  const int quad = l >> 4;
  const int role1 = w >> 2;       // 1 = layer-1 wave (4..7), 0 = layer-2 wave (0..3)
  const int idx   = w & 3;        // index within role
  const int hh    = quad & 1;     // L1 ew half (lanes<32: quad 0/1)

  // ---- overlayed weight fragments (R10 layout, verified passing) ----
  f16x8 WB[32];
  float biasL[4], wxL[4];          // role1 per-lane
  float biasB[4];                  // role0 per-lane (l<16)

  if (role1){
    #pragma unroll
    for (int g = 0; g < 4; ++g){
      #pragma unroll
      for (int h = 0; h < 2; ++h){
        const int fi = 2*g + h;
        const int nc = (8*g + 2*idx + h)*16 + col;
        #pragma unroll
        for (int k = 0; k < 4; ++k)
          WB[4*fi + k] = load_frag(w_hh1 + nc*HID1 + k*32 + quad*8);
      }
    }
    #pragma unroll
    for (int g = 0; g < 4; ++g){
      const int nc = (8*g + 2*idx + hh)*16 + col;
      biasL[g] = b_ih1[nc] + b_hh1[nc];
      wxL[g]   = w_ih1[nc];                    // w_ih1 is (512,1)
    }
    #pragma unroll
    for (int g = 0; g < 4; ++g) biasB[g] = 0.0f;
  } else {
    #pragma unroll
    for (int g = 0; g < 4; ++g){
      const int nc = (4*g + idx)*16 + col;
      biasB[g] = b_ih2[nc] + b_hh2[nc];
      biasL[g] = 0.0f; wxL[g] = 0.0f;
      #pragma unroll
      for (int k = 0; k < 4; ++k)
        WB[4*g + k] = load_frag(w_ih2 + nc*HID1 + k*32 + quad*8);
      #pragma unroll
      for (int k = 0; k < 2; ++k)
        WB[16 + 2*g + k] = load_frag(w_hh2 + nc*EMB2 + k*32 + quad*8);
    }
    #pragma unroll
    for (int k = 24; k < 32; ++k) WB[k] = WB[k - 24];  // keep array fully defined
  }

  // ---- x preload + state init ----
  xs[t]       = x[b * TB + t];
  xs[t + 512] = x[b * TB + t + 512];
  if (t < HID1) { H1[0][t] = (_Float16)0.0f; H1[1][t] = (_Float16)0.0f; }
  else if (t < HID1 + EMB2){
    H2[0][t-HID1] = (_Float16)0.0f; H2[1][t-HID1] = (_Float16)0.0f;
  }
  __syncthreads();

  float c1 = 0.0f, c2 = 0.0f;
  const f32x4 zacc = {0.0f, 0.0f, 0.0f, 0.0f};

  // persistent L2 prefetch registers (h1 fragments, ping-pong)
  f16x8 RA[4], RB[4];

  // ---- L1 iteration body ----
  auto l1_iter = [&](int rslot, int wslot, float xt){
    const f16x8* pA1 = (const f16x8*)&H1[rslot][0];
    f16x8 a1[4];
    #pragma unroll
    for (int k = 0; k < 4; ++k) a1[k] = pA1[4*k + quad];
    f32x4 acc[8];
    #pragma unroll
    for (int f = 0; f < 8; ++f) acc[f] = MFMA16(a1[0], WB[4*f], zacc);
    #pragma unroll
    for (int k = 1; k < 4; ++k){
      #pragma unroll
      for (int f = 0; f < 8; ++f) acc[f] = MFMA16(a1[k], WB[4*f + k], acc[f]);
    }
    if (l < 32){
      float g4[4];
      #pragma unroll
      for (int g = 0; g < 4; ++g)
        g4[g] = acc[2*g + hh][0] + __builtin_fmaf(xt, wxL[g], biasL[g]);
      c1 = sigmoid_f(g4[1]) * c1 + sigmoid_f(g4[0]) * tanh_f(g4[2]);
      const float hv = sigmoid_f(g4[3]) * tanh_f(c1);
      H1[wslot][32*idx + 16*hh + col] = (_Float16)hv;
    }
  };

  // ---- L2 iteration body: consume Acons (h1, lag-2, in regs), read a2
  //      (h2, lag-1) at top, prefetch Apref = next h1 fragment ----
  auto l2_iter = [&](const f16x8* Acons, f16x8* Apref,
                     int h1slot, int h2rslot, int h2wslot){
    const f16x8* pA2 = (const f16x8*)&H2[h2rslot][0];
    f16x8 a2[2];
    #pragma unroll
    for (int k = 0; k < 2; ++k) a2[k] = pA2[4*k + quad];
    const f16x8* pA1 = (const f16x8*)&H1[h1slot][0];
    #pragma unroll
    for (int k = 0; k < 4; ++k) Apref[k] = pA1[4*k + quad];

    f32x4 lo[4], hi[4];
    #pragma unroll
    for (int g = 0; g < 4; ++g){
      lo[g] = MFMA16(Acons[0], WB[4*g+0], zacc);
      hi[g] = MFMA16(Acons[2], WB[4*g+2], zacc);
    }
    #pragma unroll
    for (int g = 0; g < 4; ++g){
      lo[g] = MFMA16(Acons[1], WB[4*g+1], lo[g]);
      hi[g] = MFMA16(Acons[3], WB[4*g+3], hi[g]);
    }
    #pragma unroll
    for (int g = 0; g < 4; ++g){
      lo[g] = MFMA16(a2[0], WB[16+2*g+0], lo[g]);
      hi[g] = MFMA16(a2[1], WB[16+2*g+1], hi[g]);
    }
    if (l < 16){
      float g4[4];
      #pragma unroll
      for (int g = 0; g < 4; ++g)
        g4[g] = lo[g][0] + hi[g][0] + biasB[g];
      c2 = sigmoid_f(g4[1]) * c2 + sigmoid_f(g4[0]) * tanh_f(g4[2]);
      const float hv = sigmoid_f(g4[3]) * tanh_f(c2);
      H2[h2wslot][16*idx + l] = (_Float16)hv;
    }
  };

  // ---- iter 0: h1(0) = f(x0), no MFMA (h1(-1)=0) -> H1[0] ----
  if (role1 && l < 32){
    const float xt = xs[0];
    float g4[4];
    #pragma unroll
    for (int g = 0; g < 4; ++g) g4[g] = __builtin_fmaf(xt, wxL[g], biasL[g]);
    c1 = sigmoid_f(g4[1]) * c1 + sigmoid_f(g4[0]) * tanh_f(g4[2]);
    const float hv = sigmoid_f(g4[3]) * tanh_f(c1);
    H1[0][32*idx + 16*hh + col] = (_Float16)hv;
  }
  __syncthreads();

  // ---- iter 1 (hoisted): L1 h1(1) (reads H1[0] -> H1[1]);
  //      L2 prefetches RA = h1(0) from H1[0] ----
  if (role1){
    l1_iter(0, 1, xs[1]);
  } else {
    const f16x8* pA1 = (const f16x8*)&H1[0][0];
    #pragma unroll
    for (int k = 0; k < 4; ++k) RA[k] = pA1[4*k + quad];
  }
  __syncthreads();

  // ---- main loop: pairs (sE even, sE+1), sE = 2..1022 ----
  #pragma unroll 1
  for (int sE = 2; sE < TB; sE += 2){
    // ===== iter sE (even): L1 reads H1[1], writes H1[0];
    //       L2 consumes RA=h1(sE-2), a2 from H2[1], writes H2[0],
    //       prefetches RB = h1(sE-1) from H1[1] =====
    if (role1) l1_iter(1, 0, xs[sE]);
    else       l2_iter(RA, RB, 1, 1, 0);
    __syncthreads();

    // ===== iter sE+1 (odd): mirrored slots =====
    if (role1) l1_iter(0, 1, xs[sE+1]);
    else       l2_iter(RB, RA, 0, 0, 1);
    __syncthreads();
  }

  // ---- epilogue iter 1024 (even): L2 computes h2(1022).
  //      a2 = h2(1021) from H2[1]; consume RA = h1(1022); -> H2[0];
  //      prefetch RB = h1(1023) from H1[1]. ----
  if (!role1) l2_iter(RA, RB, 1, 1, 0);
  __syncthreads();

  // ---- iter 1025 (odd): h2(1023) -> out. a2 = h2(1022) from H2[0];
  //      consume RB = h1(1023). ----
  if (!role1){
    const f16x8* pA2 = (const f16x8*)&H2[0][0];
    f16x8 a2[2];
    #pragma unroll
    for (int k = 0; k < 2; ++k) a2[k] = pA2[4*k + quad];
    f32x4 lo[4], hi[4];
    #pragma unroll
    for (int g = 0; g < 4; ++g){
      lo[g] = MFMA16(RB[0], WB[4*g+0], zacc);
      hi[g] = MFMA16(RB[2], WB[4*g+2], zacc);
    }
    #pragma unroll
    for (int g = 0; g < 4; ++g){
      lo[g] = MFMA16(RB[1], WB[4*g+1], lo[g]);
      hi[g] = MFMA16(RB[3], WB[4*g+3], hi[g]);
    }
    #pragma unroll
    for (int g = 0; g < 4; ++g){
      lo[g] = MFMA16(a2[0], WB[16+2*g+0], lo[g]);
      hi[g] = MFMA16(a2[1], WB[16+2*g+1], hi[g]);
    }
    if (l < 16){
      float g4[4];
      #pragma unroll
      for (int g = 0; g < 4; ++g)
        g4[g] = lo[g][0] + hi[g][0] + biasB[g];
      c2 = sigmoid_f(g4[1]) * c2 + sigmoid_f(g4[0]) * tanh_f(g4[2]);
      const float hv = sigmoid_f(g4[3]) * tanh_f(c2);
      out[b * EMB2 + 16*idx + l] = hv;
    }
  }
}

extern "C" void kernel_launch(void* const* d_in, const int* in_sizes, int n_in,
                              void* d_out, int out_size, void* d_ws, size_t ws_size,
                              hipStream_t stream) {
  lstm2_kernel<<<dim3(128), dim3(512), 0, stream>>>(
      (const float*)d_in[0],   // x
      (const float*)d_in[1],   // w_ih1
      (const float*)d_in[2],   // w_hh1
      (const float*)d_in[3],   // b_ih1
      (const float*)d_in[4],   // b_hh1
      (const float*)d_in[5],   // w_ih2
      (const float*)d_in[6],   // w_hh2
      (const float*)d_in[7],   // b_ih2
      (const float*)d_in[8],   // b_hh2
      (float*)d_out);
}

// Round 4
// 1532.476 us; speedup vs baseline: 1.0138x; 1.0138x over previous
//
#include <hip/hip_runtime.h>

// 2-layer LSTM encoder, B=128, T=1024, F=1, HID=128, EMB=64.
// R13 = R12 schedule (wave specialization + L2 lag-2 register prefetch),
// scratch-spill fixed.
//   R12 passed refcheck but regressed 727->1522us; WRITE_SIZE 32->4128 KB
//   exposed the cause: the prefetch arrays RA[4]/RB[4] were passed through
//   lambda POINTER params -> SROA defeated -> arrays in scratch, per-iter
//   scratch round-trips (guide rule #20). The lag-2 theory was never tested.
//   R13 re-expresses the identical schedule with individually-NAMED registers
//   (RA0..RA3 / RB0..RB3) and token-pasting macros: every access is a
//   compile-time register name; nothing addressable remains.
// Schedule (verified passing in R12): iter s: L1 (waves 4-7) computes h1(s),
//   s in 1..1023; L2 (waves 0-3) computes h2(s-2), s in 2..1025.
//   h1(m)->H1[m&1], h2(m)->H2[m&1].
//   L2 at iter s: consumes h1(s-2) from REGISTERS (prefetched during s-1,
//   zero-wait MFMA issue at barrier release, covering L1's a1 ds_read
//   latency on the shared matrix pipe); reads a2=h2(s-3) from H2[(s-1)&1]
//   at top (latency hidden under the 16 ih-MFMAs); prefetches h1(s-1) from
//   H1[(s-1)&1] for the next iter. Two L2-only epilogue iters (h2(1022),
//   h2(1023)).

#define TB   1024
#define HID1 128
#define EMB2 64

typedef _Float16 f16x8 __attribute__((ext_vector_type(8)));
typedef float    f32x4 __attribute__((ext_vector_type(4)));

#define MFMA16(a,b,c) __builtin_amdgcn_mfma_f32_16x16x32_f16((a),(b),(c),0,0,0)

static __device__ __forceinline__ float fast_exp2(float x){
#if __has_builtin(__builtin_amdgcn_exp2f)
  return __builtin_amdgcn_exp2f(x);
#else
  return __exp2f(x);
#endif
}
static __device__ __forceinline__ float fast_rcp(float x){
#if __has_builtin(__builtin_amdgcn_rcpf)
  return __builtin_amdgcn_rcpf(x);
#else
  return 1.0f / x;
#endif
}
static __device__ __forceinline__ float sigmoid_f(float x){
  return fast_rcp(1.0f + fast_exp2(-1.44269504088896340736f * x));
}
static __device__ __forceinline__ float tanh_f(float x){
  return 1.0f - 2.0f * fast_rcp(1.0f + fast_exp2(2.88539008177792681472f * x));
}

static __device__ __forceinline__ f16x8 load_frag(const float* p){
  f16x8 r;
  #pragma unroll
  for (int j = 0; j < 8; ++j) r[j] = (_Float16)p[j];
  return r;
}

// ---- L1 iteration: 32 MFMAs depth-4, ew on 32 lanes. All names local. ----
#define L1_ITER(RSLOT, WSLOT, XT) do {                                        \
    const f16x8* pA1_ = (const f16x8*)&H1[(RSLOT)][0];                        \
    const f16x8 a1_0 = pA1_[quad],      a1_1 = pA1_[4 + quad],                \
                a1_2 = pA1_[8 + quad],  a1_3 = pA1_[12 + quad];               \
    f32x4 acc_[8];                                                            \
    _Pragma("unroll")                                                         \
    for (int f = 0; f < 8; ++f) acc_[f] = MFMA16(a1_0, WB[4*f+0], zacc);      \
    _Pragma("unroll")                                                         \
    for (int f = 0; f < 8; ++f) acc_[f] = MFMA16(a1_1, WB[4*f+1], acc_[f]);   \
    _Pragma("unroll")                                                         \
    for (int f = 0; f < 8; ++f) acc_[f] = MFMA16(a1_2, WB[4*f+2], acc_[f]);   \
    _Pragma("unroll")                                                         \
    for (int f = 0; f < 8; ++f) acc_[f] = MFMA16(a1_3, WB[4*f+3], acc_[f]);   \
    if (l < 32){                                                              \
      float g4_[4];                                                           \
      _Pragma("unroll")                                                       \
      for (int g = 0; g < 4; ++g)                                             \
        g4_[g] = acc_[2*g + hh][0] + __builtin_fmaf((XT), wxL[g], biasL[g]);  \
      c1 = sigmoid_f(g4_[1]) * c1 + sigmoid_f(g4_[0]) * tanh_f(g4_[2]);       \
      const float hv_ = sigmoid_f(g4_[3]) * tanh_f(c1);                       \
      H1[(WSLOT)][32*idx + 16*hh + col] = (_Float16)hv_;                      \
    }                                                                         \
  } while(0)

// ---- L2 iteration: consume A0..A3 (h1 lag-2, named regs), read a2 (h2
//      lag-1) at top, prefetch P0..P3 = next h1 fragment. ----
#define L2_ITER(A0,A1,A2,A3, P0,P1,P2,P3, H1SLOT, H2R, H2W) do {              \
    const f16x8* pA2_ = (const f16x8*)&H2[(H2R)][0];                          \
    const f16x8 a2_0 = pA2_[quad], a2_1 = pA2_[4 + quad];                     \
    const f16x8* pA1_ = (const f16x8*)&H1[(H1SLOT)][0];                       \
    P0 = pA1_[quad];      P1 = pA1_[4 + quad];                                \
    P2 = pA1_[8 + quad];  P3 = pA1_[12 + quad];                               \
    f32x4 lo_[4], hi_[4];                                                     \
    _Pragma("unroll")                                                         \
    for (int g = 0; g < 4; ++g){                                              \
      lo_[g] = MFMA16(A0, WB[4*g+0], zacc);                                   \
      hi_[g] = MFMA16(A2, WB[4*g+2], zacc);                                   \
    }                                                                         \
    _Pragma("unroll")                                                         \
    for (int g = 0; g < 4; ++g){                                              \
      lo_[g] = MFMA16(A1, WB[4*g+1], lo_[g]);                                 \
      hi_[g] = MFMA16(A3, WB[4*g+3], hi_[g]);                                 \
    }                                                                         \
    _Pragma("unroll")                                                         \
    for (int g = 0; g < 4; ++g){                                              \
      lo_[g] = MFMA16(a2_0, WB[16+2*g+0], lo_[g]);                            \
      hi_[g] = MFMA16(a2_1, WB[16+2*g+1], hi_[g]);                            \
    }                                                                         \
    if (l < 16){                                                              \
      float g4_[4];                                                           \
      _Pragma("unroll")                                                       \
      for (int g = 0; g < 4; ++g) g4_[g] = lo_[g][0] + hi_[g][0] + biasB[g];  \
      c2 = sigmoid_f(g4_[1]) * c2 + sigmoid_f(g4_[0]) * tanh_f(g4_[2]);       \
      const float hv_ = sigmoid_f(g4_[3]) * tanh_f(c2);                       \
      H2[(H2W)][16*idx + l] = (_Float16)hv_;                                  \
    }                                                                         \
  } while(0)

__launch_bounds__(512, 2)
__global__ void lstm2_kernel(const float* __restrict__ x,
                             const float* __restrict__ w_ih1,
                             const float* __restrict__ w_hh1,
                             const float* __restrict__ b_ih1,
                             const float* __restrict__ b_hh1,
                             const float* __restrict__ w_ih2,
                             const float* __restrict__ w_hh2,
                             const float* __restrict__ b_ih2,
                             const float* __restrict__ b_hh2,
                             float* __restrict__ out)
{
  __shared__ __align__(16) float    xs[TB];
  __shared__ __align__(16) _Float16 H1[2][HID1];  // h1 ping-pong
  __shared__ __align__(16) _Float16 H2[2][EMB2];  // h2 ping-pong

  const int t    = threadIdx.x;   // 0..511
  const int b    = blockIdx.x;    // 0..127
  const int l    = t & 63;        // lane
  const int w    = t >> 6;        // wave 0..7
  const int col  = l & 15;
  const int quad = l >> 4;
  const int role1 = w >> 2;       // 1 = layer-1 wave (4..7), 0 = layer-2 wave (0..3)
  const int idx   = w & 3;        // index within role
  const int hh    = quad & 1;     // L1 ew half (lanes<32: quad 0/1)

  // ---- overlayed weight fragments (R10 layout, verified passing) ----
  f16x8 WB[32];
  float biasL[4], wxL[4];          // role1 per-lane
  float biasB[4];                  // role0 per-lane (l<16)

  if (role1){
    #pragma unroll
    for (int g = 0; g < 4; ++g){
      #pragma unroll
      for (int h = 0; h < 2; ++h){
        const int fi = 2*g + h;
        const int nc = (8*g + 2*idx + h)*16 + col;
        #pragma unroll
        for (int k = 0; k < 4; ++k)
          WB[4*fi + k] = load_frag(w_hh1 + nc*HID1 + k*32 + quad*8);
      }
    }
    #pragma unroll
    for (int g = 0; g < 4; ++g){
      const int nc = (8*g + 2*idx + hh)*16 + col;
      biasL[g] = b_ih1[nc] + b_hh1[nc];
      wxL[g]   = w_ih1[nc];                    // w_ih1 is (512,1)
    }
    #pragma unroll
    for (int g = 0; g < 4; ++g) biasB[g] = 0.0f;
  } else {
    #pragma unroll
    for (int g = 0; g < 4; ++g){
      const int nc = (4*g + idx)*16 + col;
      biasB[g] = b_ih2[nc] + b_hh2[nc];
      biasL[g] = 0.0f; wxL[g] = 0.0f;
      #pragma unroll
      for (int k = 0; k < 4; ++k)
        WB[4*g + k] = load_frag(w_ih2 + nc*HID1 + k*32 + quad*8);
      #pragma unroll
      for (int k = 0; k < 2; ++k)
        WB[16 + 2*g + k] = load_frag(w_hh2 + nc*EMB2 + k*32 + quad*8);
    }
    #pragma unroll
    for (int k = 24; k < 32; ++k) WB[k] = WB[k - 24];  // keep array fully defined
  }

  // ---- x preload + state init ----
  xs[t]       = x[b * TB + t];
  xs[t + 512] = x[b * TB + t + 512];
  if (t < HID1) { H1[0][t] = (_Float16)0.0f; H1[1][t] = (_Float16)0.0f; }
  else if (t < HID1 + EMB2){
    H2[0][t-HID1] = (_Float16)0.0f; H2[1][t-HID1] = (_Float16)0.0f;
  }
  __syncthreads();

  float c1 = 0.0f, c2 = 0.0f;
  const f32x4 zacc = {0.0f, 0.0f, 0.0f, 0.0f};

  // persistent L2 prefetch registers (h1 fragments, ping-pong) — NAMED,
  // never indexed, never address-taken.
  f16x8 RA0, RA1, RA2, RA3, RB0, RB1, RB2, RB3;

  // ---- iter 0: h1(0) = f(x0), no MFMA (h1(-1)=0) -> H1[0] ----
  if (role1 && l < 32){
    const float xt = xs[0];
    float g4[4];
    #pragma unroll
    for (int g = 0; g < 4; ++g) g4[g] = __builtin_fmaf(xt, wxL[g], biasL[g]);
    c1 = sigmoid_f(g4[1]) * c1 + sigmoid_f(g4[0]) * tanh_f(g4[2]);
    const float hv = sigmoid_f(g4[3]) * tanh_f(c1);
    H1[0][32*idx + 16*hh + col] = (_Float16)hv;
  }
  __syncthreads();

  // ---- iter 1 (hoisted): L1 h1(1) (reads H1[0] -> H1[1]);
  //      L2 prefetches RA = h1(0) from H1[0] ----
  if (role1){
    L1_ITER(0, 1, xs[1]);
  } else {
    const f16x8* pA1 = (const f16x8*)&H1[0][0];
    RA0 = pA1[quad];      RA1 = pA1[4 + quad];
    RA2 = pA1[8 + quad];  RA3 = pA1[12 + quad];
  }
  __syncthreads();

  // ---- main loop: pairs (sE even, sE+1), sE = 2..1022 ----
  #pragma unroll 1
  for (int sE = 2; sE < TB; sE += 2){
    // iter sE (even): L1 reads H1[1] -> H1[0]; L2 consumes RA=h1(sE-2),
    // a2 from H2[1] -> H2[0], prefetches RB = h1(sE-1) from H1[1].
    if (role1) L1_ITER(1, 0, xs[sE]);
    else       L2_ITER(RA0,RA1,RA2,RA3, RB0,RB1,RB2,RB3, 1, 1, 0);
    __syncthreads();

    // iter sE+1 (odd): mirrored slots.
    if (role1) L1_ITER(0, 1, xs[sE+1]);
    else       L2_ITER(RB0,RB1,RB2,RB3, RA0,RA1,RA2,RA3, 0, 0, 1);
    __syncthreads();
  }

  // ---- epilogue iter 1024 (even): L2 computes h2(1022).
  //      a2 = h2(1021) from H2[1]; consume RA = h1(1022) -> H2[0];
  //      prefetch RB = h1(1023) from H1[1]. ----
  if (!role1) L2_ITER(RA0,RA1,RA2,RA3, RB0,RB1,RB2,RB3, 1, 1, 0);
  __syncthreads();

  // ---- iter 1025 (odd): h2(1023) -> out. a2 = h2(1022) from H2[0];
  //      consume RB = h1(1023). ----
  if (!role1){
    const f16x8* pA2 = (const f16x8*)&H2[0][0];
    const f16x8 a2_0 = pA2[quad], a2_1 = pA2[4 + quad];
    f32x4 lo[4], hi[4];
    #pragma unroll
    for (int g = 0; g < 4; ++g){
      lo[g] = MFMA16(RB0, WB[4*g+0], zacc);
      hi[g] = MFMA16(RB2, WB[4*g+2], zacc);
    }
    #pragma unroll
    for (int g = 0; g < 4; ++g){
      lo[g] = MFMA16(RB1, WB[4*g+1], lo[g]);
      hi[g] = MFMA16(RB3, WB[4*g+3], hi[g]);
    }
    #pragma unroll
    for (int g = 0; g < 4; ++g){
      lo[g] = MFMA16(a2_0, WB[16+2*g+0], lo[g]);
      hi[g] = MFMA16(a2_1, WB[16+2*g+1], hi[g]);
    }
    if (l < 16){
      float g4[4];
      #pragma unroll
      for (int g = 0; g < 4; ++g)
        g4[g] = lo[g][0] + hi[g][0] + biasB[g];
      c2 = sigmoid_f(g4[1]) * c2 + sigmoid_f(g4[0]) * tanh_f(g4[2]);
      const float hv = sigmoid_f(g4[3]) * tanh_f(c2);
      out[b * EMB2 + 16*idx + l] = hv;
    }
  }
}

extern "C" void kernel_launch(void* const* d_in, const int* in_sizes, int n_in,
                              void* d_out, int out_size, void* d_ws, size_t ws_size,
                              hipStream_t stream) {
  lstm2_kernel<<<dim3(128), dim3(512), 0, stream>>>(
      (const float*)d_in[0],   // x
      (const float*)d_in[1],   // w_ih1
      (const float*)d_in[2],   // w_hh1
      (const float*)d_in[3],   // b_ih1
      (const float*)d_in[4],   // b_hh1
      (const float*)d_in[5],   // w_ih2
      (const float*)d_in[6],   // w_hh2
      (const float*)d_in[7],   // b_ih2
      (const float*)d_in[8],   // b_hh2
      (float*)d_out);
}

// Round 5
// 706.132 us; speedup vs baseline: 2.2001x; 2.1702x over previous
//
#include <hip/hip_runtime.h>

// 2-layer LSTM encoder, B=128, T=1024, F=1, HID=128, EMB=64.
// R14 = R13 (wave specialization + L2 lag-2 register prefetch) with the REAL
// spill cause fixed.
//   R13 post-mortem: WRITE_SIZE stayed 4128 KB and VGPR_Count stayed 120 --
//   identical to R12 -- so the spill was never SROA failure; it is an
//   allocation-CAP spill. Extra writes = 4096 KB = 64 B/thread = exactly one
//   4x f16x8 prefetch set. __launch_bounds__(512,2) caps VGPRs at ~128
//   (2 blocks/CU = 4 waves/SIMD); R9 allocated exactly 128, R10 fit at 104,
//   R12/R13 demanded ~140+ -> allocator spilled the prefetch regs; per-iter
//   scratch L2-latency round-trips on the serial path doubled the step.
//   Grid = 128 blocks <= 256 CUs, so >1 block/CU never happens anyway:
//   (512,1) costs nothing and lifts the cap to >=256.
// Changes vs R13 (schedule/indexing verbatim otherwise, refcheck'd in R12/13):
//   1. __launch_bounds__(512, 1)
//   2. acc_[2*g+hh] runtime index -> explicit ternary on named elements
//      (lowers to v_cndmask, cannot reach scratch).
// Schedule: iter s: L1 (waves 4-7) computes h1(s), s in 1..1023; L2 (waves
//   0-3) computes h2(s-2), s in 2..1025. h1(m)->H1[m&1], h2(m)->H2[m&1].
//   L2 consumes h1(s-2) from regs (prefetched during s-1 -> zero-wait MFMA
//   issue at barrier release, covering L1's a1 ds_read latency on the shared
//   matrix pipe); a2=h2(s-3) read at top, hidden under 16 ih-MFMAs;
//   prefetch h1(s-1) for next iter. Two L2-only epilogue iters.

#define TB   1024
#define HID1 128
#define EMB2 64

typedef _Float16 f16x8 __attribute__((ext_vector_type(8)));
typedef float    f32x4 __attribute__((ext_vector_type(4)));

#define MFMA16(a,b,c) __builtin_amdgcn_mfma_f32_16x16x32_f16((a),(b),(c),0,0,0)

static __device__ __forceinline__ float fast_exp2(float x){
#if __has_builtin(__builtin_amdgcn_exp2f)
  return __builtin_amdgcn_exp2f(x);
#else
  return __exp2f(x);
#endif
}
static __device__ __forceinline__ float fast_rcp(float x){
#if __has_builtin(__builtin_amdgcn_rcpf)
  return __builtin_amdgcn_rcpf(x);
#else
  return 1.0f / x;
#endif
}
static __device__ __forceinline__ float sigmoid_f(float x){
  return fast_rcp(1.0f + fast_exp2(-1.44269504088896340736f * x));
}
static __device__ __forceinline__ float tanh_f(float x){
  return 1.0f - 2.0f * fast_rcp(1.0f + fast_exp2(2.88539008177792681472f * x));
}

static __device__ __forceinline__ f16x8 load_frag(const float* p){
  f16x8 r;
  #pragma unroll
  for (int j = 0; j < 8; ++j) r[j] = (_Float16)p[j];
  return r;
}

// ---- L1 iteration: 32 MFMAs depth-4, ew on 32 lanes. All names local. ----
#define L1_ITER(RSLOT, WSLOT, XT) do {                                        \
    const f16x8* pA1_ = (const f16x8*)&H1[(RSLOT)][0];                        \
    const f16x8 a1_0 = pA1_[quad],      a1_1 = pA1_[4 + quad],                \
                a1_2 = pA1_[8 + quad],  a1_3 = pA1_[12 + quad];               \
    f32x4 acc_[8];                                                            \
    _Pragma("unroll")                                                         \
    for (int f = 0; f < 8; ++f) acc_[f] = MFMA16(a1_0, WB[4*f+0], zacc);      \
    _Pragma("unroll")                                                         \
    for (int f = 0; f < 8; ++f) acc_[f] = MFMA16(a1_1, WB[4*f+1], acc_[f]);   \
    _Pragma("unroll")                                                         \
    for (int f = 0; f < 8; ++f) acc_[f] = MFMA16(a1_2, WB[4*f+2], acc_[f]);   \
    _Pragma("unroll")                                                         \
    for (int f = 0; f < 8; ++f) acc_[f] = MFMA16(a1_3, WB[4*f+3], acc_[f]);   \
    if (l < 32){                                                              \
      float g4_[4];                                                           \
      _Pragma("unroll")                                                       \
      for (int g = 0; g < 4; ++g){                                            \
        const float accv_ = hh ? acc_[2*g+1][0] : acc_[2*g][0];               \
        g4_[g] = accv_ + __builtin_fmaf((XT), wxL[g], biasL[g]);              \
      }                                                                       \
      c1 = sigmoid_f(g4_[1]) * c1 + sigmoid_f(g4_[0]) * tanh_f(g4_[2]);       \
      const float hv_ = sigmoid_f(g4_[3]) * tanh_f(c1);                       \
      H1[(WSLOT)][32*idx + 16*hh + col] = (_Float16)hv_;                      \
    }                                                                         \
  } while(0)

// ---- L2 iteration: consume A0..A3 (h1 lag-2, named regs), read a2 (h2
//      lag-1) at top, prefetch P0..P3 = next h1 fragment. ----
#define L2_ITER(A0,A1,A2,A3, P0,P1,P2,P3, H1SLOT, H2R, H2W) do {              \
    const f16x8* pA2_ = (const f16x8*)&H2[(H2R)][0];                          \
    const f16x8 a2_0 = pA2_[quad], a2_1 = pA2_[4 + quad];                     \
    const f16x8* pA1_ = (const f16x8*)&H1[(H1SLOT)][0];                       \
    P0 = pA1_[quad];      P1 = pA1_[4 + quad];                                \
    P2 = pA1_[8 + quad];  P3 = pA1_[12 + quad];                               \
    f32x4 lo_[4], hi_[4];                                                     \
    _Pragma("unroll")                                                         \
    for (int g = 0; g < 4; ++g){                                              \
      lo_[g] = MFMA16(A0, WB[4*g+0], zacc);                                   \
      hi_[g] = MFMA16(A2, WB[4*g+2], zacc);                                   \
    }                                                                         \
    _Pragma("unroll")                                                         \
    for (int g = 0; g < 4; ++g){                                              \
      lo_[g] = MFMA16(A1, WB[4*g+1], lo_[g]);                                 \
      hi_[g] = MFMA16(A3, WB[4*g+3], hi_[g]);                                 \
    }                                                                         \
    _Pragma("unroll")                                                         \
    for (int g = 0; g < 4; ++g){                                              \
      lo_[g] = MFMA16(a2_0, WB[16+2*g+0], lo_[g]);                            \
      hi_[g] = MFMA16(a2_1, WB[16+2*g+1], hi_[g]);                            \
    }                                                                         \
    if (l < 16){                                                              \
      float g4_[4];                                                           \
      _Pragma("unroll")                                                       \
      for (int g = 0; g < 4; ++g) g4_[g] = lo_[g][0] + hi_[g][0] + biasB[g];  \
      c2 = sigmoid_f(g4_[1]) * c2 + sigmoid_f(g4_[0]) * tanh_f(g4_[2]);       \
      const float hv_ = sigmoid_f(g4_[3]) * tanh_f(c2);                       \
      H2[(H2W)][16*idx + l] = (_Float16)hv_;                                  \
    }                                                                         \
  } while(0)

__launch_bounds__(512, 1)
__global__ void lstm2_kernel(const float* __restrict__ x,
                             const float* __restrict__ w_ih1,
                             const float* __restrict__ w_hh1,
                             const float* __restrict__ b_ih1,
                             const float* __restrict__ b_hh1,
                             const float* __restrict__ w_ih2,
                             const float* __restrict__ w_hh2,
                             const float* __restrict__ b_ih2,
                             const float* __restrict__ b_hh2,
                             float* __restrict__ out)
{
  __shared__ __align__(16) float    xs[TB];
  __shared__ __align__(16) _Float16 H1[2][HID1];  // h1 ping-pong
  __shared__ __align__(16) _Float16 H2[2][EMB2];  // h2 ping-pong

  const int t    = threadIdx.x;   // 0..511
  const int b    = blockIdx.x;    // 0..127
  const int l    = t & 63;        // lane
  const int w    = t >> 6;        // wave 0..7
  const int col  = l & 15;
  const int quad = l >> 4;
  const int role1 = w >> 2;       // 1 = layer-1 wave (4..7), 0 = layer-2 wave (0..3)
  const int idx   = w & 3;        // index within role
  const int hh    = quad & 1;     // L1 ew half (lanes<32: quad 0/1)

  // ---- overlayed weight fragments (R10 layout, verified passing) ----
  f16x8 WB[32];
  float biasL[4], wxL[4];          // role1 per-lane
  float biasB[4];                  // role0 per-lane (l<16)

  if (role1){
    #pragma unroll
    for (int g = 0; g < 4; ++g){
      #pragma unroll
      for (int h = 0; h < 2; ++h){
        const int fi = 2*g + h;
        const int nc = (8*g + 2*idx + h)*16 + col;
        #pragma unroll
        for (int k = 0; k < 4; ++k)
          WB[4*fi + k] = load_frag(w_hh1 + nc*HID1 + k*32 + quad*8);
      }
    }
    #pragma unroll
    for (int g = 0; g < 4; ++g){
      const int nc = (8*g + 2*idx + hh)*16 + col;
      biasL[g] = b_ih1[nc] + b_hh1[nc];
      wxL[g]   = w_ih1[nc];                    // w_ih1 is (512,1)
    }
    #pragma unroll
    for (int g = 0; g < 4; ++g) biasB[g] = 0.0f;
  } else {
    #pragma unroll
    for (int g = 0; g < 4; ++g){
      const int nc = (4*g + idx)*16 + col;
      biasB[g] = b_ih2[nc] + b_hh2[nc];
      biasL[g] = 0.0f; wxL[g] = 0.0f;
      #pragma unroll
      for (int k = 0; k < 4; ++k)
        WB[4*g + k] = load_frag(w_ih2 + nc*HID1 + k*32 + quad*8);
      #pragma unroll
      for (int k = 0; k < 2; ++k)
        WB[16 + 2*g + k] = load_frag(w_hh2 + nc*EMB2 + k*32 + quad*8);
    }
    #pragma unroll
    for (int k = 24; k < 32; ++k) WB[k] = WB[k - 24];  // keep array fully defined
  }

  // ---- x preload + state init ----
  xs[t]       = x[b * TB + t];
  xs[t + 512] = x[b * TB + t + 512];
  if (t < HID1) { H1[0][t] = (_Float16)0.0f; H1[1][t] = (_Float16)0.0f; }
  else if (t < HID1 + EMB2){
    H2[0][t-HID1] = (_Float16)0.0f; H2[1][t-HID1] = (_Float16)0.0f;
  }
  __syncthreads();

  float c1 = 0.0f, c2 = 0.0f;
  const f32x4 zacc = {0.0f, 0.0f, 0.0f, 0.0f};

  // persistent L2 prefetch registers (h1 fragments, ping-pong) — NAMED,
  // never indexed, never address-taken.
  f16x8 RA0, RA1, RA2, RA3, RB0, RB1, RB2, RB3;

  // ---- iter 0: h1(0) = f(x0), no MFMA (h1(-1)=0) -> H1[0] ----
  if (role1 && l < 32){
    const float xt = xs[0];
    float g4[4];
    #pragma unroll
    for (int g = 0; g < 4; ++g) g4[g] = __builtin_fmaf(xt, wxL[g], biasL[g]);
    c1 = sigmoid_f(g4[1]) * c1 + sigmoid_f(g4[0]) * tanh_f(g4[2]);
    const float hv = sigmoid_f(g4[3]) * tanh_f(c1);
    H1[0][32*idx + 16*hh + col] = (_Float16)hv;
  }
  __syncthreads();

  // ---- iter 1 (hoisted): L1 h1(1) (reads H1[0] -> H1[1]);
  //      L2 prefetches RA = h1(0) from H1[0] ----
  if (role1){
    L1_ITER(0, 1, xs[1]);
  } else {
    const f16x8* pA1 = (const f16x8*)&H1[0][0];
    RA0 = pA1[quad];      RA1 = pA1[4 + quad];
    RA2 = pA1[8 + quad];  RA3 = pA1[12 + quad];
  }
  __syncthreads();

  // ---- main loop: pairs (sE even, sE+1), sE = 2..1022 ----
  #pragma unroll 1
  for (int sE = 2; sE < TB; sE += 2){
    // iter sE (even): L1 reads H1[1] -> H1[0]; L2 consumes RA=h1(sE-2),
    // a2 from H2[1] -> H2[0], prefetches RB = h1(sE-1) from H1[1].
    if (role1) L1_ITER(1, 0, xs[sE]);
    else       L2_ITER(RA0,RA1,RA2,RA3, RB0,RB1,RB2,RB3, 1, 1, 0);
    __syncthreads();

    // iter sE+1 (odd): mirrored slots.
    if (role1) L1_ITER(0, 1, xs[sE+1]);
    else       L2_ITER(RB0,RB1,RB2,RB3, RA0,RA1,RA2,RA3, 0, 0, 1);
    __syncthreads();
  }

  // ---- epilogue iter 1024 (even): L2 computes h2(1022).
  //      a2 = h2(1021) from H2[1]; consume RA = h1(1022) -> H2[0];
  //      prefetch RB = h1(1023) from H1[1]. ----
  if (!role1) L2_ITER(RA0,RA1,RA2,RA3, RB0,RB1,RB2,RB3, 1, 1, 0);
  __syncthreads();

  // ---- iter 1025 (odd): h2(1023) -> out. a2 = h2(1022) from H2[0];
  //      consume RB = h1(1023). ----
  if (!role1){
    const f16x8* pA2 = (const f16x8*)&H2[0][0];
    const f16x8 a2_0 = pA2[quad], a2_1 = pA2[4 + quad];
    f32x4 lo[4], hi[4];
    #pragma unroll
    for (int g = 0; g < 4; ++g){
      lo[g] = MFMA16(RB0, WB[4*g+0], zacc);
      hi[g] = MFMA16(RB2, WB[4*g+2], zacc);
    }
    #pragma unroll
    for (int g = 0; g < 4; ++g){
      lo[g] = MFMA16(RB1, WB[4*g+1], lo[g]);
      hi[g] = MFMA16(RB3, WB[4*g+3], hi[g]);
    }
    #pragma unroll
    for (int g = 0; g < 4; ++g){
      lo[g] = MFMA16(a2_0, WB[16+2*g+0], lo[g]);
      hi[g] = MFMA16(a2_1, WB[16+2*g+1], hi[g]);
    }
    if (l < 16){
      float g4[4];
      #pragma unroll
      for (int g = 0; g < 4; ++g)
        g4[g] = lo[g][0] + hi[g][0] + biasB[g];
      c2 = sigmoid_f(g4[1]) * c2 + sigmoid_f(g4[0]) * tanh_f(g4[2]);
      const float hv = sigmoid_f(g4[3]) * tanh_f(c2);
      out[b * EMB2 + 16*idx + l] = hv;
    }
  }
}

extern "C" void kernel_launch(void* const* d_in, const int* in_sizes, int n_in,
                              void* d_out, int out_size, void* d_ws, size_t ws_size,
                              hipStream_t stream) {
  lstm2_kernel<<<dim3(128), dim3(512), 0, stream>>>(
      (const float*)d_in[0],   // x
      (const float*)d_in[1],   // w_ih1
      (const float*)d_in[2],   // w_hh1
      (const float*)d_in[3],   // b_ih1
      (const float*)d_in[4],   // b_hh1
      (const float*)d_in[5],   // w_ih2
      (const float*)d_in[6],   // w_hh2
      (const float*)d_in[7],   // b_ih2
      (const float*)d_in[8],   // b_hh2
      (float*)d_out);
}